// Round 1
// baseline (334.275 us; speedup 1.0000x reference)
//
#include <hip/hip_runtime.h>

// Problem constants (from setup_inputs): B=4, S=8, T=2048, R=256
#define T_N 2048
#define R_N 256
#define SLICES 32            // B*S
#define NELEM (SLICES * T_N * R_N)   // 16,777,216 per tensor
#define MIN_BLOCKS 1024

__global__ __launch_bounds__(256) void kmin(const float* __restrict__ x,
                                            const float* __restrict__ y,
                                            float* __restrict__ partial,
                                            float* __restrict__ out) {
    if (blockIdx.x == 0 && threadIdx.x < 4) out[threadIdx.x] = 0.0f;
    const int tid = blockIdx.x * blockDim.x + threadIdx.x;
    const int stride = gridDim.x * blockDim.x;
    const int n4 = NELEM / 4;
    const float4* __restrict__ x4 = (const float4*)x;
    const float4* __restrict__ y4 = (const float4*)y;
    float m = 3.0e38f;
    for (int i = tid; i < n4; i += stride) {
        float4 a = x4[i];
        float4 b = y4[i];
        m = fminf(m, fminf(fminf(a.x, a.y), fminf(a.z, a.w)));
        m = fminf(m, fminf(fminf(b.x, b.y), fminf(b.z, b.w)));
    }
    #pragma unroll
    for (int off = 32; off; off >>= 1) m = fminf(m, __shfl_down(m, off));
    __shared__ float sm[4];
    if ((threadIdx.x & 63) == 0) sm[threadIdx.x >> 6] = m;
    __syncthreads();
    if (threadIdx.x == 0) {
        partial[blockIdx.x] = fminf(fminf(sm[0], sm[1]), fminf(sm[2], sm[3]));
    }
}

// One block = one (slice, r-tile of 4). One wave = one problem (r column).
__global__ __launch_bounds__(256) void kmain(const float* __restrict__ x,
                                             const float* __restrict__ y,
                                             const float* __restrict__ partial,
                                             float* __restrict__ out) {
    __shared__ float U[4][T_N];
    __shared__ float V[4][T_N];
    __shared__ float red[4];

    const int tid = threadIdx.x;

    // ---- reduce global-min partials (redundant per block, 4 KiB) ----
    float m = 3.0e38f;
    for (int i = tid; i < MIN_BLOCKS; i += 256) m = fminf(m, partial[i]);
    #pragma unroll
    for (int off = 32; off; off >>= 1) m = fminf(m, __shfl_down(m, off));
    if ((tid & 63) == 0) red[tid >> 6] = m;
    __syncthreads();
    const float mn = fminf(fminf(red[0], red[1]), fminf(red[2], red[3]));
    const float sh = 1.1f * fminf(mn, 0.0f);   // x' = x - sh

    const int blk = blockIdx.x;
    const int bs = blk >> 6;     // slice 0..31
    const int rt = blk & 63;     // r-tile 0..63
    const size_t base = (size_t)bs * (T_N * R_N) + (size_t)(rt * 4);

    // ---- load 4 columns of x and y (shifted) into LDS ----
    #pragma unroll
    for (int i = 0; i < 8; ++i) {
        const int t = tid + 256 * i;
        const float4 a = *(const float4*)(x + base + (size_t)t * R_N);
        U[0][t] = a.x - sh; U[1][t] = a.y - sh; U[2][t] = a.z - sh; U[3][t] = a.w - sh;
        const float4 b = *(const float4*)(y + base + (size_t)t * R_N);
        V[0][t] = b.x - sh; V[1][t] = b.y - sh; V[2][t] = b.z - sh; V[3][t] = b.w - sh;
    }
    __syncthreads();

    const int w = tid >> 6;      // wave id = problem within tile
    const int lane = tid & 63;
    float* __restrict__ cu = U[w];
    float* __restrict__ cv = V[w];

    // ---- column sums ----
    float su = 0.0f, sv = 0.0f;
    #pragma unroll 4
    for (int c = 0; c < 32; ++c) {
        su += cu[c * 64 + lane];
        sv += cv[c * 64 + lane];
    }
    #pragma unroll
    for (int off = 32; off; off >>= 1) {
        su += __shfl_down(su, off);
        sv += __shfl_down(sv, off);
    }
    const float invU = 1.0f / __shfl(su, 0);
    const float invV = 1.0f / __shfl(sv, 0);

    // ---- in-place normalized prefix sums (CDFs), one wave per column ----
    float runu = 0.0f, runv = 0.0f;
    for (int c = 0; c < 32; ++c) {
        float a = cu[c * 64 + lane];
        float b = cv[c * 64 + lane];
        #pragma unroll
        for (int off = 1; off < 64; off <<= 1) {
            const float ta = __shfl_up(a, off);
            const float tb = __shfl_up(b, off);
            if (lane >= off) { a += ta; b += tb; }
        }
        cu[c * 64 + lane] = (runu + a) * invU;
        cv[c * 64 + lane] = (runv + b) * invV;
        runu += __shfl(a, 63);
        runv += __shfl(b, 63);
    }
    // wave-internal ordering: same wave wrote, same wave reads below (in-order LDS)

    // ---- merge-path: lane handles merged positions [d, d+64) ----
    const float INF = 3.0e38f;
    const int d = lane * 64;
    int i, j;
    if (d == 0) {
        i = 0; j = 0;
    } else {
        int lo = (d > T_N) ? (d - T_N) : 0;
        int hi = (d < T_N) ? d : T_N;
        while (lo < hi) {
            const int mid = (lo + hi) >> 1;
            if (cu[mid] <= cv[d - mid - 1]) lo = mid + 1; else hi = mid;
        }
        i = lo; j = d - lo;
    }
    float qprev = 0.0f;
    if (d > 0) {
        const float pa = (i > 0) ? cu[i - 1] : -INF;
        const float pb = (j > 0) ? cv[j - 1] : -INF;
        qprev = fmaxf(pa, pb);
    }

    float uv = (i < T_N) ? cu[i] : INF;
    float vv = (j < T_N) ? cv[j] : INF;
    float acc = 0.0f;
    const float inv_n = 1.0f / (float)T_N;
    #pragma unroll 8
    for (int s = 0; s < 64; ++s) {
        const bool takeU = (uv <= vv);
        const float q = takeU ? uv : vv;
        const float du = (float)(i < T_N - 1 ? i : T_N - 1);
        const float dv = (float)(j < T_N - 1 ? j : T_N - 1);
        const float diff = (du - dv) * inv_n;
        acc += (q - qprev) * diff * diff;
        qprev = q;
        if (takeU) { ++i; uv = (i < T_N) ? cu[i] : INF; }
        else       { ++j; vv = (j < T_N) ? cv[j] : INF; }
    }

    // ---- reduce 64 lane partials -> problem W2^2, atomic into out[b] ----
    #pragma unroll
    for (int off = 32; off; off >>= 1) acc += __shfl_down(acc, off);
    if (lane == 0) atomicAdd(&out[bs >> 3], acc);
}

extern "C" void kernel_launch(void* const* d_in, const int* in_sizes, int n_in,
                              void* d_out, int out_size, void* d_ws, size_t ws_size,
                              hipStream_t stream) {
    const float* x = (const float*)d_in[0];
    const float* y = (const float*)d_in[1];
    float* out = (float*)d_out;
    float* partial = (float*)d_ws;   // MIN_BLOCKS floats

    kmin<<<MIN_BLOCKS, 256, 0, stream>>>(x, y, partial, out);
    kmain<<<SLICES * 64, 256, 0, stream>>>(x, y, partial, out);
}

// Round 2
// 330.148 us; speedup vs baseline: 1.0125x; 1.0125x over previous
//
#include <hip/hip_runtime.h>

// Problem constants (from setup_inputs): B=4, S=8, T=2048, R=256
#define T_N 2048
#define R_N 256
#define SLICES 32                     // B*S
#define NELEM (SLICES * T_N * R_N)    // 16,777,216 per tensor
#define MIN_BLOCKS 1024
#define PADN 2112                     // 2048 + 2048/32 (pad +1 float per 32)

__device__ __forceinline__ int padi(int i) { return i + (i >> 5); }

__global__ __launch_bounds__(256) void kmin(const float* __restrict__ x,
                                            const float* __restrict__ y,
                                            float* __restrict__ partial,
                                            float* __restrict__ out) {
    if (blockIdx.x == 0 && threadIdx.x < 4) out[threadIdx.x] = 0.0f;
    const int tid = blockIdx.x * blockDim.x + threadIdx.x;
    const int stride = gridDim.x * blockDim.x;
    const int n4 = NELEM / 4;
    const float4* __restrict__ x4 = (const float4*)x;
    const float4* __restrict__ y4 = (const float4*)y;
    float m = 3.0e38f;
    for (int i = tid; i < n4; i += stride) {
        float4 a = x4[i], b = y4[i];
        m = fminf(m, fminf(fminf(a.x, a.y), fminf(a.z, a.w)));
        m = fminf(m, fminf(fminf(b.x, b.y), fminf(b.z, b.w)));
    }
    #pragma unroll
    for (int off = 32; off; off >>= 1) m = fminf(m, __shfl_down(m, off));
    __shared__ float sm[4];
    if ((threadIdx.x & 63) == 0) sm[threadIdx.x >> 6] = m;
    __syncthreads();
    if (threadIdx.x == 0)
        partial[blockIdx.x] = fminf(fminf(sm[0], sm[1]), fminf(sm[2], sm[3]));
}

// One block = one (slice, r-tile of 4). One wave = one problem (r column).
// W2^2 * n^2 = -sum_{p<n-1} u_p*(2(p-r_p)+1) + sum_{q<n-1} v_q*(2(s_q-q)-1)
// r_p = min(#{v_cdf < u_p}, n-1), s_q = min(#{u_cdf < v_q}, n-1)
// (exact Abel-summation rearrangement of the merged-quantile sum; the 11-level
//  greedy binary search below returns exactly min(count, n-1).)
__global__ __launch_bounds__(256) void kmain(const float* __restrict__ x,
                                             const float* __restrict__ y,
                                             const float* __restrict__ partial,
                                             float* __restrict__ out) {
    __shared__ float L[8 * PADN];   // per wave w: U at (2w)*PADN, V at (2w+1)*PADN
    __shared__ float red[4];
    const int tid = threadIdx.x;

    // ---- reduce global-min partials (redundant per block, 4 KiB) ----
    float m = 3.0e38f;
    for (int i = tid; i < MIN_BLOCKS; i += 256) m = fminf(m, partial[i]);
    #pragma unroll
    for (int off = 32; off; off >>= 1) m = fminf(m, __shfl_down(m, off));
    if ((tid & 63) == 0) red[tid >> 6] = m;
    __syncthreads();
    const float mn = fminf(fminf(red[0], red[1]), fminf(red[2], red[3]));
    const float sh = 1.1f * fminf(mn, 0.0f);

    const int blk = blockIdx.x;
    const int bs = blk >> 6;     // slice 0..31
    const int rt = blk & 63;     // r-tile 0..63
    const size_t base = (size_t)bs * (T_N * R_N) + (size_t)(rt * 4);

    // ---- stage 4 columns of x and y (shifted) into padded LDS ----
    #pragma unroll
    for (int i = 0; i < 8; ++i) {
        const int t = tid + 256 * i;
        const int pt = padi(t);
        const float4 a = *(const float4*)(x + base + (size_t)t * R_N);
        const float4 b = *(const float4*)(y + base + (size_t)t * R_N);
        L[0 * PADN + pt] = a.x - sh;
        L[2 * PADN + pt] = a.y - sh;
        L[4 * PADN + pt] = a.z - sh;
        L[6 * PADN + pt] = a.w - sh;
        L[1 * PADN + pt] = b.x - sh;
        L[3 * PADN + pt] = b.y - sh;
        L[5 * PADN + pt] = b.z - sh;
        L[7 * PADN + pt] = b.w - sh;
    }
    __syncthreads();

    const int w = tid >> 6;      // wave id = problem within tile
    const int l = tid & 63;
    float* __restrict__ cu = &L[(2 * w) * PADN];
    float* __restrict__ cv = &L[(2 * w + 1) * PADN];
    const int cb = l * 33;       // padded base of this lane's 32-elem chunk

    // ---- chunk sums + lane-scan + normalized CDF write-back ----
    {
        float uvr[32], vvr[32];
        float su = 0.f, sv = 0.f;
        #pragma unroll
        for (int k = 0; k < 32; ++k) { uvr[k] = cu[cb + k]; su += uvr[k]; }
        #pragma unroll
        for (int k = 0; k < 32; ++k) { vvr[k] = cv[cb + k]; sv += vvr[k]; }
        float iu = su, iv = sv;
        #pragma unroll
        for (int off = 1; off < 64; off <<= 1) {
            const float a = __shfl_up(iu, off);
            const float b = __shfl_up(iv, off);
            if (l >= off) { iu += a; iv += b; }
        }
        const float invU = 1.0f / __shfl(iu, 63);
        const float invV = 1.0f / __shfl(iv, 63);
        float ru = iu - su, rv = iv - sv;   // exclusive prefixes
        #pragma unroll
        for (int k = 0; k < 32; ++k) {
            ru += uvr[k]; cu[cb + k] = ru * invU;
            rv += vvr[k]; cv[cb + k] = rv * invV;
        }
    }
    // same-wave LDS program order => no barrier needed before the searches

    float acc = 0.0f;

    // ---- rank searches: u-keys in cv ----
    for (int g = 0; g < 4; ++g) {
        float kk[8]; int rr[8];
        #pragma unroll
        for (int j = 0; j < 8; ++j) { kk[j] = cu[cb + g * 8 + j]; rr[j] = 0; }
        #pragma unroll
        for (int s = 1024; s >= 1; s >>= 1) {
            #pragma unroll
            for (int j = 0; j < 8; ++j)
                if (cv[padi(rr[j] + s - 1)] < kk[j]) rr[j] += s;
        }
        const int pb = l * 32 + g * 8;
        #pragma unroll
        for (int j = 0; j < 8; ++j) {
            const int p = pb + j;
            const float t = kk[j] * (float)(2 * (p - rr[j]) + 1);
            acc -= (p < T_N - 1) ? t : 0.0f;
        }
    }
    // ---- rank searches: v-keys in cu ----
    for (int g = 0; g < 4; ++g) {
        float kk[8]; int rr[8];
        #pragma unroll
        for (int j = 0; j < 8; ++j) { kk[j] = cv[cb + g * 8 + j]; rr[j] = 0; }
        #pragma unroll
        for (int s = 1024; s >= 1; s >>= 1) {
            #pragma unroll
            for (int j = 0; j < 8; ++j)
                if (cu[padi(rr[j] + s - 1)] < kk[j]) rr[j] += s;
        }
        const int qb = l * 32 + g * 8;
        #pragma unroll
        for (int j = 0; j < 8; ++j) {
            const int q = qb + j;
            const float t = kk[j] * (float)(2 * (rr[j] - q) - 1);
            acc += (q < T_N - 1) ? t : 0.0f;
        }
    }

    // ---- reduce lane partials -> problem W2^2 * n^2, atomic into out[b] ----
    #pragma unroll
    for (int off = 32; off; off >>= 1) acc += __shfl_down(acc, off);
    if (l == 0)
        atomicAdd(&out[bs >> 3], acc * (1.0f / ((float)T_N * (float)T_N)));
}

extern "C" void kernel_launch(void* const* d_in, const int* in_sizes, int n_in,
                              void* d_out, int out_size, void* d_ws, size_t ws_size,
                              hipStream_t stream) {
    const float* x = (const float*)d_in[0];
    const float* y = (const float*)d_in[1];
    float* out = (float*)d_out;
    float* partial = (float*)d_ws;   // MIN_BLOCKS floats

    kmin<<<MIN_BLOCKS, 256, 0, stream>>>(x, y, partial, out);
    kmain<<<SLICES * 64, 256, 0, stream>>>(x, y, partial, out);
}

// Round 3
// 286.608 us; speedup vs baseline: 1.1663x; 1.1519x over previous
//
#include <hip/hip_runtime.h>

// Problem constants (from setup_inputs): B=4, S=8, T=2048, R=256
#define T_N 2048
#define R_N 256
#define SLICES 32                     // B*S
#define NELEM (SLICES * T_N * R_N)    // 16,777,216 per tensor
#define MIN_BLOCKS 1024
#define INFV 3.0e38f

// XOR-swizzled quad layout for each 2048-float list:
//   logical quad q stored at physical quad q ^ ((q>>3)&7).
// - staging scalar writes (consecutive t across lanes): 2-way banks (free)
// - chunk-scan b128 reads/writes (lane l -> quads 8l+m): exactly 8 words/bank (floor)
// - merge/corank reads: random quads (fine)
__device__ __forceinline__ int A_(int p) {
    const int q = p >> 2;
    return ((q ^ ((q >> 3) & 7)) << 2) | (p & 3);
}
__device__ __forceinline__ int AQ_(int q) { return q ^ ((q >> 3) & 7); }

__device__ __forceinline__ float sel8(float4 a, float4 b, int idx) {
    float4 q;
    q.x = (idx & 4) ? b.x : a.x;  q.y = (idx & 4) ? b.y : a.y;
    q.z = (idx & 4) ? b.z : a.z;  q.w = (idx & 4) ? b.w : a.w;
    const float r0 = (idx & 1) ? q.y : q.x;
    const float r1 = (idx & 1) ? q.w : q.z;
    return (idx & 2) ? r1 : r0;
}

__global__ __launch_bounds__(256) void kmin(const float* __restrict__ x,
                                            const float* __restrict__ y,
                                            float* __restrict__ partial,
                                            float* __restrict__ out) {
    if (blockIdx.x == 0 && threadIdx.x < 4) out[threadIdx.x] = 0.0f;
    const int tid = blockIdx.x * blockDim.x + threadIdx.x;
    const int stride = gridDim.x * blockDim.x;
    const int n4 = NELEM / 4;
    const float4* __restrict__ x4 = (const float4*)x;
    const float4* __restrict__ y4 = (const float4*)y;
    float m = 3.0e38f;
    for (int i = tid; i < n4; i += stride) {
        float4 a = x4[i], b = y4[i];
        m = fminf(m, fminf(fminf(a.x, a.y), fminf(a.z, a.w)));
        m = fminf(m, fminf(fminf(b.x, b.y), fminf(b.z, b.w)));
    }
    #pragma unroll
    for (int off = 32; off; off >>= 1) m = fminf(m, __shfl_down(m, off));
    __shared__ float sm[4];
    if ((threadIdx.x & 63) == 0) sm[threadIdx.x >> 6] = m;
    __syncthreads();
    if (threadIdx.x == 0)
        partial[blockIdx.x] = fminf(fminf(sm[0], sm[1]), fminf(sm[2], sm[3]));
}

// One block = one (slice, r-tile of 4). One wave = one problem.
// Exact merged-quantile sum (validated in R0), with register-window merge.
__global__ __launch_bounds__(256) void kmain(const float* __restrict__ x,
                                             const float* __restrict__ y,
                                             const float* __restrict__ partial,
                                             float* __restrict__ out) {
    __shared__ float L[8 * T_N];   // 8 lists x 2048 floats = 64 KiB
    __shared__ float red[4];
    const int tid = threadIdx.x;

    // ---- global min (redundant per block) ----
    float m = 3.0e38f;
    #pragma unroll
    for (int it = 0; it < MIN_BLOCKS / 256; ++it)
        m = fminf(m, partial[tid + 256 * it]);
    #pragma unroll
    for (int off = 32; off; off >>= 1) m = fminf(m, __shfl_down(m, off));
    if ((tid & 63) == 0) red[tid >> 6] = m;
    __syncthreads();
    const float sh = 1.1f * fminf(fminf(fminf(red[0], red[1]), fminf(red[2], red[3])), 0.0f);

    // ---- XCD-aware remap: 4 blocks sharing a 64B global line -> same XCD ----
    const int blk = blockIdx.x;
    const int xcd = blk & 7;
    const int k = blk >> 3;
    const int sub = k & 3;
    const int rest = k >> 2;
    const int rt = (((rest & 1) << 3) + xcd) * 4 + sub;   // 0..63
    const int bs = rest >> 1;                              // 0..31
    const size_t base = (size_t)bs * (T_N * R_N) + (size_t)(rt * 4);

    // ---- stage 4 columns of x and y (shifted) into swizzled LDS ----
    #pragma unroll
    for (int it = 0; it < 8; ++it) {
        const int t = tid + 256 * it;
        const int pa = A_(t);
        const float4 a = *(const float4*)(x + base + (size_t)t * R_N);
        const float4 b = *(const float4*)(y + base + (size_t)t * R_N);
        L[0 * T_N + pa] = a.x - sh;  L[2 * T_N + pa] = a.y - sh;
        L[4 * T_N + pa] = a.z - sh;  L[6 * T_N + pa] = a.w - sh;
        L[1 * T_N + pa] = b.x - sh;  L[3 * T_N + pa] = b.y - sh;
        L[5 * T_N + pa] = b.z - sh;  L[7 * T_N + pa] = b.w - sh;
    }
    __syncthreads();

    const int w = tid >> 6;
    const int l = tid & 63;
    float* __restrict__ cu = &L[(2 * w) * T_N];
    float* __restrict__ cv = &L[(2 * w + 1) * T_N];
    const int c1 = l & 7;

    // ---- per-list: chunk b128 loads, wave scan, normalized CDF write-back ----
    #pragma unroll 1
    for (int li = 0; li < 2; ++li) {
        float4* __restrict__ p4 = (float4*)(li == 0 ? cu : cv);
        float4 c[8];
        float ssum = 0.f;
        #pragma unroll
        for (int mm = 0; mm < 8; ++mm) {
            c[mm] = p4[8 * l + (mm ^ c1)];
            ssum += (c[mm].x + c[mm].y) + (c[mm].z + c[mm].w);
        }
        float inc = ssum;
        #pragma unroll
        for (int off = 1; off < 64; off <<= 1) {
            const float t2 = __shfl_up(inc, off);
            if (l >= off) inc += t2;
        }
        const float inv = 1.0f / __shfl(inc, 63);
        float run = inc - ssum;   // exclusive prefix of chunk
        #pragma unroll
        for (int mm = 0; mm < 8; ++mm) {
            float4 o;
            run += c[mm].x; o.x = run * inv;
            run += c[mm].y; o.y = run * inv;
            run += c[mm].z; o.z = run * inv;
            run += c[mm].w; o.w = run * inv;
            p4[8 * l + (mm ^ c1)] = o;
        }
    }
    // wave-local from here on: no barrier needed

    // ---- co-rank binary search: lane handles merged window [64l, 64l+64) ----
    const int d = l * 64;
    int i = 0, j = 0;
    if (d > 0) {
        int lo = (d > T_N) ? (d - T_N) : 0;
        int hi = (d < T_N) ? d : T_N;
        while (lo < hi) {
            const int mid = (lo + hi) >> 1;
            if (cu[A_(mid)] <= cv[A_(d - mid - 1)]) lo = mid + 1; else hi = mid;
        }
        i = lo; j = d - lo;
    }
    float qprev = 0.0f;
    if (d > 0) {
        const float pa_ = (i > 0) ? cu[A_(i - 1)] : -INFV;
        const float pb_ = (j > 0) ? cv[A_(j - 1)] : -INFV;
        qprev = fmaxf(pa_, pb_);
    }

    // ---- register-window merge: 64 steps, quad-buffered b128 refills ----
    float4* __restrict__ cu4 = (float4*)cu;
    float4* __restrict__ cv4 = (float4*)cv;
    int qau = i & ~3;
    int qav = j & ~3;
    float4 U0 = cu4[AQ_(min(qau >> 2, 511))];
    float4 U1 = cu4[AQ_(min((qau >> 2) + 1, 511))];
    float4 V0 = cv4[AQ_(min(qav >> 2, 511))];
    float4 V1 = cv4[AQ_(min((qav >> 2) + 1, 511))];

    float acc = 0.f;
    #pragma unroll 1
    for (int g = 0; g < 16; ++g) {
        #pragma unroll
        for (int s4 = 0; s4 < 4; ++s4) {
            const float uv = (i < T_N) ? sel8(U0, U1, i - qau) : INFV;
            const float vv = (j < T_N) ? sel8(V0, V1, j - qav) : INFV;
            const bool take = (uv <= vv);
            const float q = take ? uv : vv;
            const float dd = (float)(min(i, T_N - 1) - min(j, T_N - 1));
            acc += (q - qprev) * dd * dd;
            qprev = q;
            i += take ? 1 : 0;
            j += take ? 0 : 1;
        }
        if (i >= qau + 4) { U0 = U1; U1 = cu4[AQ_(min((qau >> 2) + 2, 511))]; qau += 4; }
        if (j >= qav + 4) { V0 = V1; V1 = cv4[AQ_(min((qav >> 2) + 2, 511))]; qav += 4; }
    }

    // ---- reduce lane partials, scale by 1/n^2, atomic into out[b] ----
    #pragma unroll
    for (int off = 32; off; off >>= 1) acc += __shfl_down(acc, off);
    if (l == 0)
        atomicAdd(&out[bs >> 3], acc * (1.0f / ((float)T_N * (float)T_N)));
}

extern "C" void kernel_launch(void* const* d_in, const int* in_sizes, int n_in,
                              void* d_out, int out_size, void* d_ws, size_t ws_size,
                              hipStream_t stream) {
    const float* x = (const float*)d_in[0];
    const float* y = (const float*)d_in[1];
    float* out = (float*)d_out;
    float* partial = (float*)d_ws;   // MIN_BLOCKS floats

    kmin<<<MIN_BLOCKS, 256, 0, stream>>>(x, y, partial, out);
    kmain<<<SLICES * 64, 256, 0, stream>>>(x, y, partial, out);
}

// Round 4
// 205.064 us; speedup vs baseline: 1.6301x; 1.3976x over previous
//
#include <hip/hip_runtime.h>

// Problem constants (from setup_inputs): B=4, S=8, T=2048, R=256
#define T_N 2048
#define R_N 256
#define SLICES 32                     // B*S
#define NELEM (SLICES * T_N * R_N)    // 16,777,216 per tensor
#define MIN_BLOCKS 1024
#define INFV 3.0e38f

__global__ __launch_bounds__(256) void kmin(const float* __restrict__ x,
                                            const float* __restrict__ y,
                                            float* __restrict__ partial,
                                            float* __restrict__ out) {
    if (blockIdx.x == 0 && threadIdx.x < 4) out[threadIdx.x] = 0.0f;
    const int tid = blockIdx.x * blockDim.x + threadIdx.x;
    const int stride = gridDim.x * blockDim.x;
    const int n4 = NELEM / 4;
    const float4* __restrict__ x4 = (const float4*)x;
    const float4* __restrict__ y4 = (const float4*)y;
    float m = 3.0e38f;
    for (int i = tid; i < n4; i += stride) {
        float4 a = x4[i], b = y4[i];
        m = fminf(m, fminf(fminf(a.x, a.y), fminf(a.z, a.w)));
        m = fminf(m, fminf(fminf(b.x, b.y), fminf(b.z, b.w)));
    }
    #pragma unroll
    for (int off = 32; off; off >>= 1) m = fminf(m, __shfl_down(m, off));
    __shared__ float sm[4];
    if ((threadIdx.x & 63) == 0) sm[threadIdx.x >> 6] = m;
    __syncthreads();
    if (threadIdx.x == 0)
        partial[blockIdx.x] = fminf(fminf(sm[0], sm[1]), fminf(sm[2], sm[3]));
}

// 1024-thread block = 4 problems (one float4 of r-columns), 4 waves/problem.
// 64 KiB LDS -> 2 blocks/CU; VGPR<=64 (launch_bounds) -> 32 waves/CU = 100% occ.
// Exact merged-quantile sum (validated R0/R2), merge window = 16 elems/lane,
// scalar ds_read with 1-ahead prefetch (latency hidden by 8 waves/SIMD TLP).
__global__ __launch_bounds__(1024, 8) void kmain(const float* __restrict__ x,
                                                 const float* __restrict__ y,
                                                 const float* __restrict__ partial,
                                                 float* __restrict__ out) {
    __shared__ float L[8 * T_N];      // problem p: U at (2p)*T_N, V at (2p+1)*T_N
    __shared__ float red16[16];
    __shared__ float psum[4][2][4];   // [problem][list][wave-chunk] scan partials
    __shared__ float pacc[4][4];      // [problem][wave] result partials

    const int tid = threadIdx.x;
    const int w = tid >> 6;           // wave 0..15
    const int lane = tid & 63;

    // ---- phase 0: global min (partial[1024], one element per thread) ----
    {
        float m = partial[tid];
        #pragma unroll
        for (int off = 32; off; off >>= 1) m = fminf(m, __shfl_down(m, off));
        if (lane == 0) red16[w] = m;
    }
    __syncthreads();
    float mn = red16[0];
    #pragma unroll
    for (int k = 1; k < 16; ++k) mn = fminf(mn, red16[k]);
    const float sh = 1.1f * fminf(mn, 0.0f);

    // ---- XCD-aware remap: 4 blocks sharing a 64B global line -> same XCD ----
    const int blk = blockIdx.x;
    const int xcd = blk & 7;
    const int k2 = blk >> 3;
    const int sub = k2 & 3;
    const int rest = k2 >> 2;
    const int rt = (((rest & 1) << 3) + xcd) * 4 + sub;   // 0..63
    const int bs = rest >> 1;                              // 0..31
    const size_t base = (size_t)bs * (T_N * R_N) + (size_t)(rt * 4);

    // ---- staging: 4 columns of x and y (shifted) into linear LDS ----
    #pragma unroll
    for (int it = 0; it < 2; ++it) {
        const int t = tid + 1024 * it;
        const float4 a = *(const float4*)(x + base + (size_t)t * R_N);
        const float4 b = *(const float4*)(y + base + (size_t)t * R_N);
        L[0 * T_N + t] = a.x - sh;  L[2 * T_N + t] = a.y - sh;
        L[4 * T_N + t] = a.z - sh;  L[6 * T_N + t] = a.w - sh;
        L[1 * T_N + t] = b.x - sh;  L[3 * T_N + t] = b.y - sh;
        L[5 * T_N + t] = b.z - sh;  L[7 * T_N + t] = b.w - sh;
    }
    __syncthreads();

    const int p  = w >> 2;            // problem 0..3
    const int wl = w & 3;             // wave within problem
    const int pl = (wl << 6) | lane;  // problem-lane 0..255
    float* __restrict__ cu = &L[(2 * p) * T_N];
    float* __restrict__ cv = &L[(2 * p + 1) * T_N];

    // ---- scan: lane owns elems [8*pl, 8*pl+8) = quads 2pl, 2pl+1 ----
    {
        float4* __restrict__ cu4 = (float4*)cu;
        float4* __restrict__ cv4 = (float4*)cv;
        float4 u0 = cu4[2 * pl], u1 = cu4[2 * pl + 1];
        float4 v0 = cv4[2 * pl], v1 = cv4[2 * pl + 1];
        const float su = ((u0.x + u0.y) + (u0.z + u0.w)) + ((u1.x + u1.y) + (u1.z + u1.w));
        const float sv = ((v0.x + v0.y) + (v0.z + v0.w)) + ((v1.x + v1.y) + (v1.z + v1.w));
        float iu = su, iv = sv;
        #pragma unroll
        for (int off = 1; off < 64; off <<= 1) {
            const float a = __shfl_up(iu, off);
            const float b = __shfl_up(iv, off);
            if (lane >= off) { iu += a; iv += b; }
        }
        if (lane == 63) { psum[p][0][wl] = iu; psum[p][1][wl] = iv; }
        __syncthreads();
        float prefU = 0.f, totU = 0.f, prefV = 0.f, totV = 0.f;
        #pragma unroll
        for (int k = 0; k < 4; ++k) {
            const float a = psum[p][0][k], b = psum[p][1][k];
            totU += a; totV += b;
            if (k < wl) { prefU += a; prefV += b; }
        }
        const float invU = 1.0f / totU, invV = 1.0f / totV;
        float ru = prefU + (iu - su);
        float rv = prefV + (iv - sv);
        float4 o;
        ru += u0.x; o.x = ru * invU; ru += u0.y; o.y = ru * invU;
        ru += u0.z; o.z = ru * invU; ru += u0.w; o.w = ru * invU;
        cu4[2 * pl] = o;
        ru += u1.x; o.x = ru * invU; ru += u1.y; o.y = ru * invU;
        ru += u1.z; o.z = ru * invU; ru += u1.w; o.w = ru * invU;
        cu4[2 * pl + 1] = o;
        rv += v0.x; o.x = rv * invV; rv += v0.y; o.y = rv * invV;
        rv += v0.z; o.z = rv * invV; rv += v0.w; o.w = rv * invV;
        cv4[2 * pl] = o;
        rv += v1.x; o.x = rv * invV; rv += v1.y; o.y = rv * invV;
        rv += v1.z; o.z = rv * invV; rv += v1.w; o.w = rv * invV;
        cv4[2 * pl + 1] = o;
    }
    __syncthreads();

    // ---- co-rank binary search: lane handles merged window [16*pl, 16*pl+16) ----
    const int d = pl << 4;
    int i = 0, j = 0;
    if (d > 0) {
        int lo = (d > T_N) ? (d - T_N) : 0;
        int hi = (d < T_N) ? d : T_N;
        while (lo < hi) {
            const int mid = (lo + hi) >> 1;
            if (cu[mid] <= cv[d - mid - 1]) lo = mid + 1; else hi = mid;
        }
        i = lo; j = d - lo;
    }
    float qprev = 0.0f;
    if (d > 0) {
        const float pa_ = (i > 0) ? cu[i - 1] : -INFV;
        const float pb_ = (j > 0) ? cv[j - 1] : -INFV;
        qprev = fmaxf(pa_, pb_);
    }

    float uv, vv;
    {
        const float t1 = cu[min(i, T_N - 1)];
        const float t2 = cv[min(j, T_N - 1)];
        uv = (i < T_N) ? t1 : INFV;
        vv = (j < T_N) ? t2 : INFV;
    }
    float pu = cu[min(i + 1, T_N - 1)];
    float pv = cv[min(j + 1, T_N - 1)];

    float acc = 0.0f;
    #pragma unroll
    for (int s = 0; s < 16; ++s) {
        const bool take = (uv <= vv);
        const float q = take ? uv : vv;
        const float dd = (float)(min(i, T_N - 1) - min(j, T_N - 1));
        acc += (q - qprev) * dd * dd;
        qprev = q;
        i += take ? 1 : 0;
        j += take ? 0 : 1;
        uv = take ? ((i < T_N) ? pu : INFV) : uv;
        vv = take ? vv : ((j < T_N) ? pv : INFV);
        if (s < 15) {
            pu = cu[min(i + 1, T_N - 1)];
            pv = cv[min(j + 1, T_N - 1)];
        }
    }

    // ---- reduce: wave -> LDS -> one atomic per block ----
    #pragma unroll
    for (int off = 32; off; off >>= 1) acc += __shfl_down(acc, off);
    if (lane == 0) pacc[p][wl] = acc;
    __syncthreads();
    if (tid == 0) {
        float r = 0.f;
        #pragma unroll
        for (int pp = 0; pp < 4; ++pp)
            r += (pacc[pp][0] + pacc[pp][1]) + (pacc[pp][2] + pacc[pp][3]);
        atomicAdd(&out[bs >> 3], r * (1.0f / ((float)T_N * (float)T_N)));
    }
}

extern "C" void kernel_launch(void* const* d_in, const int* in_sizes, int n_in,
                              void* d_out, int out_size, void* d_ws, size_t ws_size,
                              hipStream_t stream) {
    const float* x = (const float*)d_in[0];
    const float* y = (const float*)d_in[1];
    float* out = (float*)d_out;
    float* partial = (float*)d_ws;   // MIN_BLOCKS floats

    kmin<<<MIN_BLOCKS, 256, 0, stream>>>(x, y, partial, out);
    kmain<<<SLICES * 64, 1024, 0, stream>>>(x, y, partial, out);
}